// Round 1
// baseline (1823.216 us; speedup 1.0000x reference)
//
#include <hip/hip_runtime.h>

// ---------------------------------------------------------------------------
// LennardJones per-atom energy.
// Inputs (d_in order): positions[N,3] f32, cell[3,3] f32, sigma_tab[4,4] f32,
//   eps_tab[4,4] f32, shift_tab[4,4] f32, species[N] i32, pair_i[P] i32,
//   pair_j[P] i32, shifts[P,3] i32.
// Output: energy[N] f32, scatter-add 0.5*e to both endpoints of each pair.
// ---------------------------------------------------------------------------

__global__ void lj_zero_kernel(float* __restrict__ out, int n) {
    int i = blockIdx.x * blockDim.x + threadIdx.x;
    if (i < n) out[i] = 0.0f;
}

__device__ __forceinline__ void lj_one_pair(
    int i, int j, float fx, float fy, float fz,
    const float* __restrict__ pos,
    const int* __restrict__ species,
    const float* s_sig6, const float* s_eps4, const float* s_shift,
    float c00, float c01, float c02,
    float c10, float c11, float c12,
    float c20, float c21, float c22,
    float* __restrict__ energy)
{
    float pix = pos[3 * i], piy = pos[3 * i + 1], piz = pos[3 * i + 2];
    float pjx = pos[3 * j], pjy = pos[3 * j + 1], pjz = pos[3 * j + 2];
    // d = pos_j - pos_i + shifts(row-vec) @ cell
    float dx = pjx - pix + fx * c00 + fy * c10 + fz * c20;
    float dy = pjy - piy + fx * c01 + fy * c11 + fz * c21;
    float dz = pjz - piz + fx * c02 + fy * c12 + fz * c22;
    float r2 = dx * dx + dy * dy + dz * dz;
    float r6 = r2 * r2 * r2;
    int si = species[i];
    int sj = species[j];
    int idx = si * 4 + sj;
    float sr6 = s_sig6[idx] / r6;
    float sr12 = sr6 * sr6;
    float e = s_eps4[idx] * (sr12 - sr6) - s_shift[idx];
    float he = 0.5f * e;
    atomicAdd(energy + i, he);
    atomicAdd(energy + j, he);
}

__global__ __launch_bounds__(256) void lj_pairs_kernel(
    const float* __restrict__ pos,
    const float* __restrict__ cell,
    const float* __restrict__ sigma_tab,
    const float* __restrict__ eps_tab,
    const float* __restrict__ shift_tab,
    const int* __restrict__ species,
    const int* __restrict__ pair_i,
    const int* __restrict__ pair_j,
    const int* __restrict__ shifts,
    float* __restrict__ energy,
    int P)
{
    __shared__ float s_sig6[16];
    __shared__ float s_eps4[16];
    __shared__ float s_shift[16];
    __shared__ float s_cell[9];
    int t = threadIdx.x;
    if (t < 16) {
        float s = sigma_tab[t];
        float s3 = s * s * s;
        s_sig6[t] = s3 * s3;
        s_eps4[t] = 4.0f * eps_tab[t];
        s_shift[t] = shift_tab[t];
    }
    if (t < 9) s_cell[t] = cell[t];
    __syncthreads();

    float c00 = s_cell[0], c01 = s_cell[1], c02 = s_cell[2];
    float c10 = s_cell[3], c11 = s_cell[4], c12 = s_cell[5];
    float c20 = s_cell[6], c21 = s_cell[7], c22 = s_cell[8];

    long base = (long)(blockIdx.x * (long)blockDim.x + t) * 4;
    if (base + 3 < P) {
        // Vectorized index loads: base%4==0 -> 16B-aligned int4; shifts offset
        // base*3 is a multiple of 12 ints -> 48B-aligned.
        int4 pi4 = *(const int4*)(pair_i + base);
        int4 pj4 = *(const int4*)(pair_j + base);
        int4 sA = *(const int4*)(shifts + base * 3);
        int4 sB = *(const int4*)(shifts + base * 3 + 4);
        int4 sC = *(const int4*)(shifts + base * 3 + 8);
        int pis[4] = {pi4.x, pi4.y, pi4.z, pi4.w};
        int pjs[4] = {pj4.x, pj4.y, pj4.z, pj4.w};
        int shv[12] = {sA.x, sA.y, sA.z, sA.w, sB.x, sB.y, sB.z, sB.w,
                       sC.x, sC.y, sC.z, sC.w};
#pragma unroll
        for (int k = 0; k < 4; ++k) {
            lj_one_pair(pis[k], pjs[k],
                        (float)shv[3 * k], (float)shv[3 * k + 1], (float)shv[3 * k + 2],
                        pos, species, s_sig6, s_eps4, s_shift,
                        c00, c01, c02, c10, c11, c12, c20, c21, c22, energy);
        }
    } else {
        for (long p = base; p < P; ++p) {
            lj_one_pair(pair_i[p], pair_j[p],
                        (float)shifts[3 * p], (float)shifts[3 * p + 1], (float)shifts[3 * p + 2],
                        pos, species, s_sig6, s_eps4, s_shift,
                        c00, c01, c02, c10, c11, c12, c20, c21, c22, energy);
        }
    }
}

extern "C" void kernel_launch(void* const* d_in, const int* in_sizes, int n_in,
                              void* d_out, int out_size, void* d_ws, size_t ws_size,
                              hipStream_t stream) {
    const float* positions = (const float*)d_in[0];
    const float* cell      = (const float*)d_in[1];
    const float* sigma_tab = (const float*)d_in[2];
    const float* eps_tab   = (const float*)d_in[3];
    const float* shift_tab = (const float*)d_in[4];
    const int*   species   = (const int*)d_in[5];
    const int*   pair_i    = (const int*)d_in[6];
    const int*   pair_j    = (const int*)d_in[7];
    const int*   shifts    = (const int*)d_in[8];
    float* energy = (float*)d_out;

    const int N = out_size;          // number of atoms
    const int P = in_sizes[6];       // number of pairs

    // d_out is poisoned (0xAA) before every timed launch: zero it first.
    {
        int threads = 256;
        int blocks = (N + threads - 1) / threads;
        lj_zero_kernel<<<blocks, threads, 0, stream>>>(energy, N);
    }
    {
        int threads = 256;
        long nthreads_needed = ((long)P + 3) / 4;
        int blocks = (int)((nthreads_needed + threads - 1) / threads);
        lj_pairs_kernel<<<blocks, threads, 0, stream>>>(
            positions, cell, sigma_tab, eps_tab, shift_tab, species,
            pair_i, pair_j, shifts, energy, P);
    }
}